// Round 12
// baseline (370.106 us; speedup 1.0000x reference)
//
#include <hip/hip_runtime.h>

#define LEAKY(v) ((v) > 0.0f ? (v) : 0.01f * (v))
#define NBUK_MAX 512  // supports N <= 131072 (bucket = dst >> 8); N < 2^24 for packing

// ---- bf16 helpers ----------------------------------------------------------
__device__ __forceinline__ unsigned short f2bf(float f) {
    unsigned u = __float_as_uint(f);
    u += 0x7fffu + ((u >> 16) & 1u);  // round-to-nearest-even
    return (unsigned short)(u >> 16);
}
__device__ __forceinline__ float4 bf4_to_f4(uint2 u) {
    float4 r;
    r.x = __uint_as_float(u.x << 16);
    r.y = __uint_as_float(u.x & 0xffff0000u);
    r.z = __uint_as_float(u.y << 16);
    r.w = __uint_as_float(u.y & 0xffff0000u);
    return r;
}

// ---------------------------------------------------------------------------
// int64-vs-int32 edge_index detection.
// ---------------------------------------------------------------------------
__device__ __forceinline__ int detect_is64(const unsigned* ei, int E) {
    __shared__ int is64_s;
    if (threadIdx.x == 0) {
        int z = 1;
        int limit = 2 * E < 128 ? 2 * E : 128;
        for (int i = 1; i < limit; i += 2)
            if (ei[i] != 0u) { z = 0; break; }
        is64_s = z;
    }
    __syncthreads();
    return is64_s;
}

// ---------------------------------------------------------------------------
// Pass A: decode edge_index -> s32/d32 (coalesced) + per-block bucket counts.
// ---------------------------------------------------------------------------
__global__ __launch_bounds__(256) void bucket_count_kernel(
    const unsigned* __restrict__ ei, int* __restrict__ s32, int* __restrict__ d32,
    int* __restrict__ gcount, int E, int nblk, int nbuk, int ch) {
    __shared__ int hist[NBUK_MAX];
    int is64 = detect_is64(ei, E);
    for (int i = threadIdx.x; i < nbuk; i += 256) hist[i] = 0;
    __syncthreads();
    int base = blockIdx.x * ch;
    int lim = min(base + ch, E);
    for (int e = base + threadIdx.x; e < lim; e += 256) {
        int s, d;
        if (is64) {
            s = (int)ei[2 * (size_t)e];
            d = (int)ei[2 * (size_t)E + 2 * (size_t)e];
        } else {
            s = (int)ei[e];
            d = (int)ei[(size_t)E + e];
        }
        s32[e] = s;
        d32[e] = d;
        atomicAdd(&hist[d >> 8], 1);
    }
    __syncthreads();
    for (int i = threadIdx.x; i < nbuk; i += 256)
        gcount[(size_t)i * nblk + blockIdx.x] = hist[i];
}

// Pass B (merged B1+B2): single block, 512 threads. Thread t sums gcount row t,
// then exclusive-scan -> bbase[0..nbuk], bbase[nbuk]=E, row_ofs[N]=E.
__global__ __launch_bounds__(512) void bucket_scan_kernel(
    const int* __restrict__ gcount, int* __restrict__ bbase,
    int* __restrict__ row_ofs, int nblk, int nbuk, int N, int E) {
    __shared__ int s[512];
    int t = threadIdx.x;
    int sum = 0;
    if (t < nbuk) {
        const int* row = gcount + (size_t)t * nblk;
        for (int i = 0; i < nblk; ++i) sum += row[i];
    }
    s[t] = sum;
    __syncthreads();
    for (int off = 1; off < 512; off <<= 1) {
        int add = (t >= off) ? s[t - off] : 0;
        __syncthreads();
        s[t] += add;
        __syncthreads();
    }
    if (t < nbuk) bbase[t] = s[t] - sum;
    if (t == 0) { bbase[nbuk] = E; row_ofs[N] = E; }
}

// Pass B3: per-bucket exclusive scan of gcount row + bucket base (in place).
__global__ __launch_bounds__(256) void scan_gcount_kernel(
    int* __restrict__ gcount, const int* __restrict__ bbase, int nblk) {
    __shared__ int s[256];
    int t = threadIdx.x;
    int v = (t < nblk) ? gcount[(size_t)blockIdx.x * nblk + t] : 0;
    s[t] = v;
    __syncthreads();
    for (int off = 1; off < 256; off <<= 1) {
        int add = (t >= off) ? s[t - off] : 0;
        __syncthreads();
        s[t] += add;
        __syncthreads();
    }
    if (t < nblk)
        gcount[(size_t)blockIdx.x * nblk + t] = bbase[blockIdx.x] + s[t] - v;
}

// Pass C: scatter edges into bucket-grouped PACKED es_tmp = (d&255)<<24 | src.
__global__ __launch_bounds__(256) void bucket_scatter_kernel(
    const int* __restrict__ s32, const int* __restrict__ d32,
    const int* __restrict__ gofs, unsigned* __restrict__ es_tmp,
    int E, int nblk, int nbuk, int ch) {
    __shared__ int cur[NBUK_MAX];
    for (int i = threadIdx.x; i < nbuk; i += 256)
        cur[i] = gofs[(size_t)i * nblk + blockIdx.x];
    __syncthreads();
    int base = blockIdx.x * ch;
    int lim = min(base + ch, E);
    for (int e = base + threadIdx.x; e < lim; e += 256) {
        int s = s32[e], d = d32[e];
        int p = atomicAdd(&cur[d >> 8], 1);
        es_tmp[p] = ((unsigned)(d & 255) << 24) | (unsigned)s;
    }
}

// Pass D (+cvt fused): per-bucket node counting sort -> es, row_ofs, dinv;
// then converts this bucket's 256 x-rows to xb = bf16(x * dinv).
__global__ __launch_bounds__(256) void bucket_sortcvt_kernel(
    const unsigned* __restrict__ es_tmp, const int* __restrict__ bbase,
    int* __restrict__ es, int* __restrict__ row_ofs, float* __restrict__ dinv,
    const float* __restrict__ x, ushort4* __restrict__ xb, int N) {
    __shared__ int hist[256];
    __shared__ int lofs[256];
    __shared__ float sdinv[256];
    int b = blockIdx.x;
    int t = threadIdx.x;
    int beg = bbase[b], end = bbase[b + 1];
    hist[t] = 0;
    __syncthreads();
    for (int j = beg + t; j < end; j += 256)
        atomicAdd(&hist[es_tmp[j] >> 24], 1);
    __syncthreads();
    int v = hist[t];
    lofs[t] = v;
    __syncthreads();
    for (int off = 1; off < 256; off <<= 1) {
        int add = (t >= off) ? lofs[t - off] : 0;
        __syncthreads();
        lofs[t] += add;
        __syncthreads();
    }
    int excl = lofs[t] - v;
    int node = (b << 8) + t;
    float dv = rsqrtf((float)v + 1.0f);
    if (node <= N) row_ofs[node] = beg + excl;
    if (node < N) dinv[node] = dv;
    sdinv[t] = dv;
    __syncthreads();
    lofs[t] = beg + excl;  // running cursor
    __syncthreads();
    for (int j = beg + t; j < end; j += 256) {
        unsigned ed = es_tmp[j];
        int p = atomicAdd(&lofs[ed >> 24], 1);
        es[p] = (int)(ed & 0xFFFFFFu);
    }
    // cvt: xb rows for this bucket's nodes (16 float4-quads per node)
    int qbase = (b << 8) * 16;
    for (int q = t; q < 256 * 16; q += 256) {
        int nl = q >> 4;
        int n = (b << 8) + nl;
        if (n >= N) break;
        float dn = sdinv[nl];
        float4 vv = ((const float4*)x)[qbase + q];
        ushort4 o;
        o.x = f2bf(vv.x * dn); o.y = f2bf(vv.y * dn);
        o.z = f2bf(vv.z * dn); o.w = f2bf(vv.w * dn);
        xb[qbase + q] = o;
    }
}

// ---------------------------------------------------------------------------
// F=64 bf16 gather over PRE-SCALED rows h'[n]=h[n]*dinv[n]:
//   out[n] = bf16((sum_e h'[src_e] + h'[n]) * dinv[n])
// wave/node; 4 groups x 16 lanes x uint2; 4-deep = 16 edge rows in flight.
// ---------------------------------------------------------------------------
__global__ __launch_bounds__(256) void gather64_bf16_kernel(
    const unsigned short* __restrict__ hb, const int* __restrict__ es,
    const int* __restrict__ row_ofs, const float* __restrict__ dinv,
    unsigned short* __restrict__ agg, int N) {
    int node = (blockIdx.x * blockDim.x + threadIdx.x) >> 6;
    if (node >= N) return;
    int lane = threadIdx.x & 63;
    int g = lane >> 4, l = lane & 15;
    int beg = row_ofs[node], end = row_ofs[node + 1];
    float dd = dinv[node];

    float4 acc = make_float4(0.f, 0.f, 0.f, 0.f);
    for (int base = beg; base < end; base += 16) {
        int s[4]; float m[4]; uint2 hv[4];
#pragma unroll
        for (int u = 0; u < 4; ++u) {
            int j = base + 4 * u + g;
            bool v = j < end;
            m[u] = v ? 1.0f : 0.0f;
            s[u] = es[v ? j : beg];
        }
#pragma unroll
        for (int u = 0; u < 4; ++u)
            hv[u] = *(const uint2*)&hb[(size_t)s[u] * 64 + 4 * l];
#pragma unroll
        for (int u = 0; u < 4; ++u) {
            float4 hh = bf4_to_f4(hv[u]);
            acc.x = fmaf(hh.x, m[u], acc.x); acc.y = fmaf(hh.y, m[u], acc.y);
            acc.z = fmaf(hh.z, m[u], acc.z); acc.w = fmaf(hh.w, m[u], acc.w);
        }
    }
#pragma unroll
    for (int mask = 16; mask <= 32; mask <<= 1) {
        acc.x += __shfl_xor(acc.x, mask);
        acc.y += __shfl_xor(acc.y, mask);
        acc.z += __shfl_xor(acc.z, mask);
        acc.w += __shfl_xor(acc.w, mask);
    }
    if (g == 0) {
        float4 sv = bf4_to_f4(*(const uint2*)&hb[(size_t)node * 64 + 4 * l]);
        ushort4 o;
        o.x = f2bf((acc.x + sv.x) * dd); o.y = f2bf((acc.y + sv.y) * dd);
        o.z = f2bf((acc.z + sv.z) * dd); o.w = f2bf((acc.w + sv.w) * dd);
        *(ushort4*)&agg[(size_t)node * 64 + 4 * l] = o;
    }
}

// ---------------------------------------------------------------------------
// F=40 bf16 gather over PRE-SCALED rows; 6 groups x 10 lanes x uint2;
// 3-deep = 18 edges in flight.  r = (sum_e h'[src] + h'[n]) * dd (+ b)
// PRESCALE_LEAKY: apply leaky then re-scale by dd (feeds next gather).
// Output always bf16.
// ---------------------------------------------------------------------------
template <bool BIAS, bool PRESCALE_LEAKY>
__global__ __launch_bounds__(256) void gather40_bf16_kernel(
    const unsigned short* __restrict__ hb, const int* __restrict__ es,
    const int* __restrict__ row_ofs, const float* __restrict__ dinv,
    const float* __restrict__ b, unsigned short* __restrict__ agg, int N) {
    int node = (blockIdx.x * blockDim.x + threadIdx.x) >> 6;
    if (node >= N) return;
    int lane = threadIdx.x & 63;
    int g = lane / 10;
    int l = lane - g * 10;
    bool lv = lane < 60;
    int beg = row_ofs[node], end = row_ofs[node + 1];
    float dd = dinv[node];

    float4 acc = make_float4(0.f, 0.f, 0.f, 0.f);
    for (int base = beg; base < end; base += 18) {
        int s[3]; float m[3]; uint2 hv[3];
#pragma unroll
        for (int u = 0; u < 3; ++u) {
            int j = base + 6 * u + g;
            bool v = lv && (j < end);
            m[u] = v ? 1.0f : 0.0f;
            s[u] = es[v ? j : beg];
        }
#pragma unroll
        for (int u = 0; u < 3; ++u)
            hv[u] = *(const uint2*)&hb[(size_t)s[u] * 40 + 4 * l];
#pragma unroll
        for (int u = 0; u < 3; ++u) {
            float4 hh = bf4_to_f4(hv[u]);
            acc.x = fmaf(hh.x, m[u], acc.x); acc.y = fmaf(hh.y, m[u], acc.y);
            acc.z = fmaf(hh.z, m[u], acc.z); acc.w = fmaf(hh.w, m[u], acc.w);
        }
    }
    float4 r = acc;
#pragma unroll
    for (int o = 10; o <= 50; o += 10) {
        r.x += __shfl(acc.x, lane + o);
        r.y += __shfl(acc.y, lane + o);
        r.z += __shfl(acc.z, lane + o);
        r.w += __shfl(acc.w, lane + o);
    }
    if (lane < 10) {
        float4 sv = bf4_to_f4(*(const uint2*)&hb[(size_t)node * 40 + 4 * l]);
        r.x = (r.x + sv.x) * dd; r.y = (r.y + sv.y) * dd;
        r.z = (r.z + sv.z) * dd; r.w = (r.w + sv.w) * dd;
        if (BIAS) {
            float4 bv = *(const float4*)&b[4 * l];
            r.x += bv.x; r.y += bv.y; r.z += bv.z; r.w += bv.w;
        }
        if (PRESCALE_LEAKY) {
            r.x = LEAKY(r.x); r.y = LEAKY(r.y); r.z = LEAKY(r.z); r.w = LEAKY(r.w);
            r.x *= dd; r.y *= dd; r.z *= dd; r.w *= dd;
        }
        ushort4 o;
        o.x = f2bf(r.x); o.y = f2bf(r.y); o.z = f2bf(r.z); o.w = f2bf(r.w);
        *(ushort4*)&agg[(size_t)node * 40 + 4 * l] = o;
    }
}

// ---------------------------------------------------------------------------
// Register-tiled GEMM with bf16 input: h[n,m] = sum_k act(x[n,k])*W[k,m] (+b).
// OUT bf16 (M%4==0); SCALE: pre-multiply stored row by dinv[n].
// ---------------------------------------------------------------------------
template <int K, int M, bool ACT, bool BIAS, bool SCALE>
__global__ __launch_bounds__(256) void gemm_tiled_bf16(
    const unsigned short* __restrict__ x, const float* __restrict__ W,
    const float* __restrict__ b, const float* __restrict__ dinv,
    unsigned short* __restrict__ hv, int N) {
    constexpr int MT = 4;
    constexpr int MC = (M + MT - 1) / MT;
    constexpr int MP = MC * MT;
    constexpr int NR = 256 / MC;
    constexpr int NT = 4;
    constexpr int BN = NR * NT;
    static_assert(K % 4 == 0 && M % 4 == 0, "K,M multiples of 4");

    __shared__ float ws[K * MP];
    for (int i = threadIdx.x; i < K * MP; i += 256) {
        int k = i / MP, m = i - k * MP;
        ws[i] = (m < M) ? W[k * M + m] : 0.0f;
    }
    __syncthreads();

    const int c = threadIdx.x % MC;
    const int r = threadIdx.x / MC;
    if (r >= NR) return;
    const int n0 = blockIdx.x * BN + r * NT;

    float acc[NT][MT];
#pragma unroll
    for (int i = 0; i < NT; ++i)
#pragma unroll
        for (int j = 0; j < MT; ++j) {
            int m = c * MT + j;
            acc[i][j] = (BIAS && m < M) ? b[m] : 0.0f;
        }

    for (int k = 0; k < K; k += 4) {
        float4 wv[4];
#pragma unroll
        for (int kk = 0; kk < 4; ++kk)
            wv[kk] = *(const float4*)&ws[(k + kk) * MP + c * MT];
#pragma unroll
        for (int i = 0; i < NT; ++i) {
            int n = n0 + i;
            if (n < N) {
                float4 xv = bf4_to_f4(*(const uint2*)&x[(size_t)n * K + k]);
                if (ACT) {
                    xv.x = LEAKY(xv.x); xv.y = LEAKY(xv.y);
                    xv.z = LEAKY(xv.z); xv.w = LEAKY(xv.w);
                }
                const float xs[4] = {xv.x, xv.y, xv.z, xv.w};
#pragma unroll
                for (int kk = 0; kk < 4; ++kk) {
                    const float* wp = (const float*)&wv[kk];
#pragma unroll
                    for (int j = 0; j < MT; ++j)
                        acc[i][j] = fmaf(xs[kk], wp[j], acc[i][j]);
                }
            }
        }
    }

#pragma unroll
    for (int i = 0; i < NT; ++i) {
        int n = n0 + i;
        if (n >= N) continue;
        float sc = SCALE ? dinv[n] : 1.0f;
        int m = c * MT;
        ushort4 o;
        o.x = f2bf(acc[i][0] * sc); o.y = f2bf(acc[i][1] * sc);
        o.z = f2bf(acc[i][2] * sc); o.w = f2bf(acc[i][3] * sc);
        *(ushort4*)&hv[(size_t)n * M + m] = o;
    }
}

// ---------------------------------------------------------------------------
// Fused L3-GEMM (40->50, +b3) + leaky + head (50x10, +bl) + log_softmax.
// Input P is bf16 (40/row).
// ---------------------------------------------------------------------------
__global__ __launch_bounds__(256) void l3head_kernel(
    const unsigned short* __restrict__ P, const float* __restrict__ W3,
    const float* __restrict__ b3, const float* __restrict__ Wl,
    const float* __restrict__ bl, float* __restrict__ out, int N) {
    __shared__ float w3s[40 * 50];
    __shared__ float b3s[50];
    __shared__ float wls[50 * 10];
    __shared__ float bls[10];
    for (int i = threadIdx.x; i < 2000; i += 256) w3s[i] = W3[i];
    for (int i = threadIdx.x; i < 500; i += 256) wls[i] = Wl[i];
    if (threadIdx.x < 50) b3s[threadIdx.x] = b3[threadIdx.x];
    if (threadIdx.x < 10) bls[threadIdx.x] = bl[threadIdx.x];
    __syncthreads();
    int n = blockIdx.x * blockDim.x + threadIdx.x;
    if (n >= N) return;

    float p[40];
    const uint2* pr = (const uint2*)(P + (size_t)n * 40);
#pragma unroll
    for (int q = 0; q < 10; ++q) {
        float4 t = bf4_to_f4(pr[q]);
        p[4 * q + 0] = t.x; p[4 * q + 1] = t.y; p[4 * q + 2] = t.z; p[4 * q + 3] = t.w;
    }
    float logits[10];
#pragma unroll
    for (int j = 0; j < 10; ++j) logits[j] = bls[j];
    for (int m = 0; m < 50; ++m) {
        float acc = b3s[m];
#pragma unroll
        for (int k = 0; k < 40; ++k) acc = fmaf(p[k], w3s[k * 50 + m], acc);
        float v = LEAKY(acc);
#pragma unroll
        for (int j = 0; j < 10; ++j) logits[j] = fmaf(v, wls[m * 10 + j], logits[j]);
    }
    float mx = logits[0];
#pragma unroll
    for (int j = 1; j < 10; ++j) mx = fmaxf(mx, logits[j]);
    float s = 0.0f;
#pragma unroll
    for (int j = 0; j < 10; ++j) s += __expf(logits[j] - mx);
    float lse = __logf(s) + mx;
    float* op = out + (size_t)n * 10;
#pragma unroll
    for (int j = 0; j < 10; ++j) op[j] = logits[j] - lse;
}

extern "C" void kernel_launch(void* const* d_in, const int* in_sizes, int n_in,
                              void* d_out, int out_size, void* d_ws, size_t ws_size,
                              hipStream_t stream) {
    const float* x  = (const float*)d_in[0];
    const unsigned* ei = (const unsigned*)d_in[1];
    const float* W1 = (const float*)d_in[2];
    const float* b1 = (const float*)d_in[3];
    const float* W2 = (const float*)d_in[4];
    const float* b2 = (const float*)d_in[5];
    const float* W3 = (const float*)d_in[6];
    const float* b3 = (const float*)d_in[7];
    const float* Wl = (const float*)d_in[8];
    const float* bl = (const float*)d_in[9];
    float* out = (float*)d_out;

    const int N = in_sizes[0] / 64;
    const int E = in_sizes[1] / 2;

    // counting-sort geometry
    int ch = 4096;
    int nblk = (E + ch - 1) / ch;
    if (nblk > 256) { ch = (E + 255) / 256; nblk = (E + ch - 1) / ch; }
    const int nbuk = (N + 255) >> 8;  // <= 512

    char* wp = (char*)d_ws;
    auto alloc = [&](size_t bytes) {
        char* p = wp;
        wp += (bytes + 255) & ~(size_t)255;
        return p;
    };
    int*   es      = (int*)alloc((size_t)E * 4);
    float* dinv    = (float*)alloc((size_t)N * 4);
    int*   row_ofs = (int*)alloc((size_t)(N + 1) * 4);
    int*   gcount  = (int*)alloc((size_t)nbuk * nblk * 4);
    int*   bbase   = (int*)alloc((size_t)(NBUK_MAX + 1) * 4);
    char*  Pr      = (char*)alloc((size_t)N * 64 * 4);  // 25.6 MB region
    char*  Ar      = (char*)alloc((size_t)N * 80 * 4);  // 32 MB region

    // aliases (strictly sequential lifetimes):
    int*      s32    = (int*)Pr;                 // passes A-C
    int*      d32    = (int*)Pr + E;
    unsigned* es_tmp = (unsigned*)Ar;            // packed, passes C-D (E*4 B)
    size_t xb_off = (((size_t)E * 4) + 255) & ~(size_t)255;
    unsigned short* xb = (unsigned short*)(Ar + xb_off);  // bf16 x', dead after gather64
    unsigned short* Pg = (unsigned short*)Pr;    // gather64 out bf16 (12.8 MB); over s32/d32
    unsigned short* A  = (unsigned short*)Ar;    // gemm1 out bf16 (16 MB); over es_tmp+xb
    unsigned short* Pb = (unsigned short*)Pr;    // gemm2 out bf16 (8 MB); over Pg
    unsigned short* Ab = (unsigned short*)(Ar + (size_t)N * 80 * 4 - (size_t)N * 40 * 2);
    unsigned short* P3 = (unsigned short*)Pr;    // gather40-L3 out bf16 (8 MB); over Pb

    const int B = 256;

    // ---- CSR build: atomic-free counting sort (+fused x->bf16 cvt) ----
    bucket_count_kernel<<<nblk, B, 0, stream>>>(ei, s32, d32, gcount, E, nblk, nbuk, ch);
    bucket_scan_kernel<<<1, 512, 0, stream>>>(gcount, bbase, row_ofs, nblk, nbuk, N, E);
    scan_gcount_kernel<<<nbuk, B, 0, stream>>>(gcount, bbase, nblk);
    bucket_scatter_kernel<<<nblk, B, 0, stream>>>(s32, d32, gcount, es_tmp, E, nblk, nbuk, ch);
    bucket_sortcvt_kernel<<<nbuk, B, 0, stream>>>(es_tmp, bbase, es, row_ofs, dinv,
                                                  x, (ushort4*)xb, N);

    const int gblocks = (N * 64 + B - 1) / B;  // one wave per node

    auto gb = [&](int M) {
        int MC = (M + 3) / 4;
        int BN = (256 / MC) * 4;
        return (N + BN - 1) / BN;
    };

    // L1: agg(xb) -> Pg bf16, then GEMM1 (+b1) -> A bf16
    gather64_bf16_kernel<<<gblocks, B, 0, stream>>>(xb, es, row_ofs, dinv, Pg, N);
    gemm_tiled_bf16<64, 80, false, true, false><<<gb(80), B, 0, stream>>>(Pg, W1, b1, nullptr, A, N);

    // L2: GEMM2: Pb = bf16((leaky(A)@W2)*dinv); gather(+b2) -> leaky*dinv -> Ab bf16
    gemm_tiled_bf16<80, 40, true, false, true><<<gb(40), B, 0, stream>>>(A, W2, nullptr, dinv, Pb, N);
    gather40_bf16_kernel<true, true><<<gblocks, B, 0, stream>>>(Pb, es, row_ofs, dinv, b2, Ab, N);

    // L3: agg(Ab) -> P3 bf16, then fused GEMM+head
    gather40_bf16_kernel<false, false><<<gblocks, B, 0, stream>>>(Ab, es, row_ofs, dinv, nullptr, P3, N);
    l3head_kernel<<<(N + B - 1) / B, B, 0, stream>>>(P3, W3, b3, Wl, bl, out, N);
}

// Round 13
// 322.925 us; speedup vs baseline: 1.1461x; 1.1461x over previous
//
#include <hip/hip_runtime.h>

#define LEAKY(v) ((v) > 0.0f ? (v) : 0.01f * (v))
#define NBUK_MAX 512  // supports N <= 131072 (bucket = dst >> 8); N < 2^24 for packing

// ---- bf16 helpers ----------------------------------------------------------
__device__ __forceinline__ unsigned short f2bf(float f) {
    unsigned u = __float_as_uint(f);
    u += 0x7fffu + ((u >> 16) & 1u);  // round-to-nearest-even
    return (unsigned short)(u >> 16);
}
__device__ __forceinline__ float4 bf4_to_f4(uint2 u) {
    float4 r;
    r.x = __uint_as_float(u.x << 16);
    r.y = __uint_as_float(u.x & 0xffff0000u);
    r.z = __uint_as_float(u.y << 16);
    r.w = __uint_as_float(u.y & 0xffff0000u);
    return r;
}

// ---------------------------------------------------------------------------
// int64-vs-int32 edge_index detection.
// ---------------------------------------------------------------------------
__device__ __forceinline__ int detect_is64(const unsigned* ei, int E) {
    __shared__ int is64_s;
    if (threadIdx.x == 0) {
        int z = 1;
        int limit = 2 * E < 128 ? 2 * E : 128;
        for (int i = 1; i < limit; i += 2)
            if (ei[i] != 0u) { z = 0; break; }
        is64_s = z;
    }
    __syncthreads();
    return is64_s;
}

// ---------------------------------------------------------------------------
// Pass A: decode edge_index -> s32/d32 (coalesced) + per-block bucket counts.
// ---------------------------------------------------------------------------
__global__ __launch_bounds__(256) void bucket_count_kernel(
    const unsigned* __restrict__ ei, int* __restrict__ s32, int* __restrict__ d32,
    int* __restrict__ gcount, int E, int nblk, int nbuk, int ch) {
    __shared__ int hist[NBUK_MAX];
    int is64 = detect_is64(ei, E);
    for (int i = threadIdx.x; i < nbuk; i += 256) hist[i] = 0;
    __syncthreads();
    int base = blockIdx.x * ch;
    int lim = min(base + ch, E);
    for (int e = base + threadIdx.x; e < lim; e += 256) {
        int s, d;
        if (is64) {
            s = (int)ei[2 * (size_t)e];
            d = (int)ei[2 * (size_t)E + 2 * (size_t)e];
        } else {
            s = (int)ei[e];
            d = (int)ei[(size_t)E + e];
        }
        s32[e] = s;
        d32[e] = d;
        atomicAdd(&hist[d >> 8], 1);
    }
    __syncthreads();
    for (int i = threadIdx.x; i < nbuk; i += 256)
        gcount[(size_t)i * nblk + blockIdx.x] = hist[i];
}

// Pass B1: per-bucket totals (one block per bucket, parallel tree reduce).
__global__ __launch_bounds__(256) void bucket_total_kernel(
    const int* __restrict__ gcount, int* __restrict__ btot, int nblk) {
    __shared__ int s[256];
    int sum = 0;
    for (int i = threadIdx.x; i < nblk; i += 256)
        sum += gcount[(size_t)blockIdx.x * nblk + i];
    s[threadIdx.x] = sum;
    __syncthreads();
    for (int off = 128; off > 0; off >>= 1) {
        if (threadIdx.x < off) s[threadIdx.x] += s[threadIdx.x + off];
        __syncthreads();
    }
    if (threadIdx.x == 0) btot[blockIdx.x] = s[0];
}

// Pass B2: exclusive scan of bucket totals -> bbase[0..nbuk], + row_ofs[N]=E.
__global__ __launch_bounds__(512) void scan_btot_kernel(
    const int* __restrict__ btot, int* __restrict__ bbase,
    int* __restrict__ row_ofs, int nbuk, int N, int E) {
    __shared__ int s[512];
    int t = threadIdx.x;
    int v = (t < nbuk) ? btot[t] : 0;
    s[t] = v;
    __syncthreads();
    for (int off = 1; off < 512; off <<= 1) {
        int add = (t >= off) ? s[t - off] : 0;
        __syncthreads();
        s[t] += add;
        __syncthreads();
    }
    if (t < nbuk) bbase[t] = s[t] - v;
    if (t == 0) { bbase[nbuk] = E; row_ofs[N] = E; }
}

// Pass B3: per-bucket exclusive scan of gcount row + bucket base (in place).
__global__ __launch_bounds__(256) void scan_gcount_kernel(
    int* __restrict__ gcount, const int* __restrict__ bbase, int nblk) {
    __shared__ int s[256];
    int t = threadIdx.x;
    int v = (t < nblk) ? gcount[(size_t)blockIdx.x * nblk + t] : 0;
    s[t] = v;
    __syncthreads();
    for (int off = 1; off < 256; off <<= 1) {
        int add = (t >= off) ? s[t - off] : 0;
        __syncthreads();
        s[t] += add;
        __syncthreads();
    }
    if (t < nblk)
        gcount[(size_t)blockIdx.x * nblk + t] = bbase[blockIdx.x] + s[t] - v;
}

// Pass C: scatter edges into bucket-grouped PACKED es_tmp = (d&255)<<24 | src.
__global__ __launch_bounds__(256) void bucket_scatter_kernel(
    const int* __restrict__ s32, const int* __restrict__ d32,
    const int* __restrict__ gofs, unsigned* __restrict__ es_tmp,
    int E, int nblk, int nbuk, int ch) {
    __shared__ int cur[NBUK_MAX];
    for (int i = threadIdx.x; i < nbuk; i += 256)
        cur[i] = gofs[(size_t)i * nblk + blockIdx.x];
    __syncthreads();
    int base = blockIdx.x * ch;
    int lim = min(base + ch, E);
    for (int e = base + threadIdx.x; e < lim; e += 256) {
        int s = s32[e], d = d32[e];
        int p = atomicAdd(&cur[d >> 8], 1);
        es_tmp[p] = ((unsigned)(d & 255) << 24) | (unsigned)s;
    }
}

// Pass D (+cvt fused): per-bucket node counting sort -> es, row_ofs, dinv;
// then converts this bucket's 256 x-rows to xb = bf16(x * dinv).
__global__ __launch_bounds__(256) void bucket_sortcvt_kernel(
    const unsigned* __restrict__ es_tmp, const int* __restrict__ bbase,
    int* __restrict__ es, int* __restrict__ row_ofs, float* __restrict__ dinv,
    const float* __restrict__ x, ushort4* __restrict__ xb, int N) {
    __shared__ int hist[256];
    __shared__ int lofs[256];
    __shared__ float sdinv[256];
    int b = blockIdx.x;
    int t = threadIdx.x;
    int beg = bbase[b], end = bbase[b + 1];
    hist[t] = 0;
    __syncthreads();
    for (int j = beg + t; j < end; j += 256)
        atomicAdd(&hist[es_tmp[j] >> 24], 1);
    __syncthreads();
    int v = hist[t];
    lofs[t] = v;
    __syncthreads();
    for (int off = 1; off < 256; off <<= 1) {
        int add = (t >= off) ? lofs[t - off] : 0;
        __syncthreads();
        lofs[t] += add;
        __syncthreads();
    }
    int excl = lofs[t] - v;
    int node = (b << 8) + t;
    float dv = rsqrtf((float)v + 1.0f);
    if (node <= N) row_ofs[node] = beg + excl;
    if (node < N) dinv[node] = dv;
    sdinv[t] = dv;
    __syncthreads();
    lofs[t] = beg + excl;  // running cursor
    __syncthreads();
    for (int j = beg + t; j < end; j += 256) {
        unsigned ed = es_tmp[j];
        int p = atomicAdd(&lofs[ed >> 24], 1);
        es[p] = (int)(ed & 0xFFFFFFu);
    }
    // cvt: xb rows for this bucket's nodes (16 float4-quads per node)
    int qbase = (b << 8) * 16;
    for (int q = t; q < 256 * 16; q += 256) {
        int nl = q >> 4;
        int n = (b << 8) + nl;
        if (n >= N) break;
        float dn = sdinv[nl];
        float4 vv = ((const float4*)x)[qbase + q];
        ushort4 o;
        o.x = f2bf(vv.x * dn); o.y = f2bf(vv.y * dn);
        o.z = f2bf(vv.z * dn); o.w = f2bf(vv.w * dn);
        xb[qbase + q] = o;
    }
}

// ---------------------------------------------------------------------------
// F=64 bf16 gather over PRE-SCALED rows h'[n]=h[n]*dinv[n]:
//   out[n] = bf16((sum_e h'[src_e] + h'[n]) * dinv[n])
// wave/node; 4 groups x 16 lanes x uint2; 4-deep = 16 edge rows in flight.
// ---------------------------------------------------------------------------
__global__ __launch_bounds__(256) void gather64_bf16_kernel(
    const unsigned short* __restrict__ hb, const int* __restrict__ es,
    const int* __restrict__ row_ofs, const float* __restrict__ dinv,
    unsigned short* __restrict__ agg, int N) {
    int node = (blockIdx.x * blockDim.x + threadIdx.x) >> 6;
    if (node >= N) return;
    int lane = threadIdx.x & 63;
    int g = lane >> 4, l = lane & 15;
    int beg = row_ofs[node], end = row_ofs[node + 1];
    float dd = dinv[node];

    float4 acc = make_float4(0.f, 0.f, 0.f, 0.f);
    for (int base = beg; base < end; base += 16) {
        int s[4]; float m[4]; uint2 hv[4];
#pragma unroll
        for (int u = 0; u < 4; ++u) {
            int j = base + 4 * u + g;
            bool v = j < end;
            m[u] = v ? 1.0f : 0.0f;
            s[u] = es[v ? j : beg];
        }
#pragma unroll
        for (int u = 0; u < 4; ++u)
            hv[u] = *(const uint2*)&hb[(size_t)s[u] * 64 + 4 * l];
#pragma unroll
        for (int u = 0; u < 4; ++u) {
            float4 hh = bf4_to_f4(hv[u]);
            acc.x = fmaf(hh.x, m[u], acc.x); acc.y = fmaf(hh.y, m[u], acc.y);
            acc.z = fmaf(hh.z, m[u], acc.z); acc.w = fmaf(hh.w, m[u], acc.w);
        }
    }
#pragma unroll
    for (int mask = 16; mask <= 32; mask <<= 1) {
        acc.x += __shfl_xor(acc.x, mask);
        acc.y += __shfl_xor(acc.y, mask);
        acc.z += __shfl_xor(acc.z, mask);
        acc.w += __shfl_xor(acc.w, mask);
    }
    if (g == 0) {
        float4 sv = bf4_to_f4(*(const uint2*)&hb[(size_t)node * 64 + 4 * l]);
        ushort4 o;
        o.x = f2bf((acc.x + sv.x) * dd); o.y = f2bf((acc.y + sv.y) * dd);
        o.z = f2bf((acc.z + sv.z) * dd); o.w = f2bf((acc.w + sv.w) * dd);
        *(ushort4*)&agg[(size_t)node * 64 + 4 * l] = o;
    }
}

// ---------------------------------------------------------------------------
// F=40 bf16 gather over PRE-SCALED rows; 6 groups x 10 lanes x uint2;
// 3-deep = 18 edges in flight.  r = (sum_e h'[src] + h'[n]) * dd (+ b)
// PRESCALE_LEAKY: apply leaky then re-scale by dd (feeds next gather).
// Output always bf16.
// ---------------------------------------------------------------------------
template <bool BIAS, bool PRESCALE_LEAKY>
__global__ __launch_bounds__(256) void gather40_bf16_kernel(
    const unsigned short* __restrict__ hb, const int* __restrict__ es,
    const int* __restrict__ row_ofs, const float* __restrict__ dinv,
    const float* __restrict__ b, unsigned short* __restrict__ agg, int N) {
    int node = (blockIdx.x * blockDim.x + threadIdx.x) >> 6;
    if (node >= N) return;
    int lane = threadIdx.x & 63;
    int g = lane / 10;
    int l = lane - g * 10;
    bool lv = lane < 60;
    int beg = row_ofs[node], end = row_ofs[node + 1];
    float dd = dinv[node];

    float4 acc = make_float4(0.f, 0.f, 0.f, 0.f);
    for (int base = beg; base < end; base += 18) {
        int s[3]; float m[3]; uint2 hv[3];
#pragma unroll
        for (int u = 0; u < 3; ++u) {
            int j = base + 6 * u + g;
            bool v = lv && (j < end);
            m[u] = v ? 1.0f : 0.0f;
            s[u] = es[v ? j : beg];
        }
#pragma unroll
        for (int u = 0; u < 3; ++u)
            hv[u] = *(const uint2*)&hb[(size_t)s[u] * 40 + 4 * l];
#pragma unroll
        for (int u = 0; u < 3; ++u) {
            float4 hh = bf4_to_f4(hv[u]);
            acc.x = fmaf(hh.x, m[u], acc.x); acc.y = fmaf(hh.y, m[u], acc.y);
            acc.z = fmaf(hh.z, m[u], acc.z); acc.w = fmaf(hh.w, m[u], acc.w);
        }
    }
    float4 r = acc;
#pragma unroll
    for (int o = 10; o <= 50; o += 10) {
        r.x += __shfl(acc.x, lane + o);
        r.y += __shfl(acc.y, lane + o);
        r.z += __shfl(acc.z, lane + o);
        r.w += __shfl(acc.w, lane + o);
    }
    if (lane < 10) {
        float4 sv = bf4_to_f4(*(const uint2*)&hb[(size_t)node * 40 + 4 * l]);
        r.x = (r.x + sv.x) * dd; r.y = (r.y + sv.y) * dd;
        r.z = (r.z + sv.z) * dd; r.w = (r.w + sv.w) * dd;
        if (BIAS) {
            float4 bv = *(const float4*)&b[4 * l];
            r.x += bv.x; r.y += bv.y; r.z += bv.z; r.w += bv.w;
        }
        if (PRESCALE_LEAKY) {
            r.x = LEAKY(r.x); r.y = LEAKY(r.y); r.z = LEAKY(r.z); r.w = LEAKY(r.w);
            r.x *= dd; r.y *= dd; r.z *= dd; r.w *= dd;
        }
        ushort4 o;
        o.x = f2bf(r.x); o.y = f2bf(r.y); o.z = f2bf(r.z); o.w = f2bf(r.w);
        *(ushort4*)&agg[(size_t)node * 40 + 4 * l] = o;
    }
}

// ---------------------------------------------------------------------------
// Register-tiled GEMM with bf16 input: h[n,m] = sum_k act(x[n,k])*W[k,m] (+b).
// OUT bf16 (M%4==0); SCALE: pre-multiply stored row by dinv[n].
// ---------------------------------------------------------------------------
template <int K, int M, bool ACT, bool BIAS, bool SCALE>
__global__ __launch_bounds__(256) void gemm_tiled_bf16(
    const unsigned short* __restrict__ x, const float* __restrict__ W,
    const float* __restrict__ b, const float* __restrict__ dinv,
    unsigned short* __restrict__ hv, int N) {
    constexpr int MT = 4;
    constexpr int MC = (M + MT - 1) / MT;
    constexpr int MP = MC * MT;
    constexpr int NR = 256 / MC;
    constexpr int NT = 4;
    constexpr int BN = NR * NT;
    static_assert(K % 4 == 0 && M % 4 == 0, "K,M multiples of 4");

    __shared__ float ws[K * MP];
    for (int i = threadIdx.x; i < K * MP; i += 256) {
        int k = i / MP, m = i - k * MP;
        ws[i] = (m < M) ? W[k * M + m] : 0.0f;
    }
    __syncthreads();

    const int c = threadIdx.x % MC;
    const int r = threadIdx.x / MC;
    if (r >= NR) return;
    const int n0 = blockIdx.x * BN + r * NT;

    float acc[NT][MT];
#pragma unroll
    for (int i = 0; i < NT; ++i)
#pragma unroll
        for (int j = 0; j < MT; ++j) {
            int m = c * MT + j;
            acc[i][j] = (BIAS && m < M) ? b[m] : 0.0f;
        }

    for (int k = 0; k < K; k += 4) {
        float4 wv[4];
#pragma unroll
        for (int kk = 0; kk < 4; ++kk)
            wv[kk] = *(const float4*)&ws[(k + kk) * MP + c * MT];
#pragma unroll
        for (int i = 0; i < NT; ++i) {
            int n = n0 + i;
            if (n < N) {
                float4 xv = bf4_to_f4(*(const uint2*)&x[(size_t)n * K + k]);
                if (ACT) {
                    xv.x = LEAKY(xv.x); xv.y = LEAKY(xv.y);
                    xv.z = LEAKY(xv.z); xv.w = LEAKY(xv.w);
                }
                const float xs[4] = {xv.x, xv.y, xv.z, xv.w};
#pragma unroll
                for (int kk = 0; kk < 4; ++kk) {
                    const float* wp = (const float*)&wv[kk];
#pragma unroll
                    for (int j = 0; j < MT; ++j)
                        acc[i][j] = fmaf(xs[kk], wp[j], acc[i][j]);
                }
            }
        }
    }

#pragma unroll
    for (int i = 0; i < NT; ++i) {
        int n = n0 + i;
        if (n >= N) continue;
        float sc = SCALE ? dinv[n] : 1.0f;
        int m = c * MT;
        ushort4 o;
        o.x = f2bf(acc[i][0] * sc); o.y = f2bf(acc[i][1] * sc);
        o.z = f2bf(acc[i][2] * sc); o.w = f2bf(acc[i][3] * sc);
        *(ushort4*)&hv[(size_t)n * M + m] = o;
    }
}

// ---------------------------------------------------------------------------
// Fused L3-GEMM (40->50, +b3) + leaky + head (50x10, +bl) + log_softmax.
// Input P is bf16 (40/row).
// ---------------------------------------------------------------------------
__global__ __launch_bounds__(256) void l3head_kernel(
    const unsigned short* __restrict__ P, const float* __restrict__ W3,
    const float* __restrict__ b3, const float* __restrict__ Wl,
    const float* __restrict__ bl, float* __restrict__ out, int N) {
    __shared__ float w3s[40 * 50];
    __shared__ float b3s[50];
    __shared__ float wls[50 * 10];
    __shared__ float bls[10];
    for (int i = threadIdx.x; i < 2000; i += 256) w3s[i] = W3[i];
    for (int i = threadIdx.x; i < 500; i += 256) wls[i] = Wl[i];
    if (threadIdx.x < 50) b3s[threadIdx.x] = b3[threadIdx.x];
    if (threadIdx.x < 10) bls[threadIdx.x] = bl[threadIdx.x];
    __syncthreads();
    int n = blockIdx.x * blockDim.x + threadIdx.x;
    if (n >= N) return;

    float p[40];
    const uint2* pr = (const uint2*)(P + (size_t)n * 40);
#pragma unroll
    for (int q = 0; q < 10; ++q) {
        float4 t = bf4_to_f4(pr[q]);
        p[4 * q + 0] = t.x; p[4 * q + 1] = t.y; p[4 * q + 2] = t.z; p[4 * q + 3] = t.w;
    }
    float logits[10];
#pragma unroll
    for (int j = 0; j < 10; ++j) logits[j] = bls[j];
    for (int m = 0; m < 50; ++m) {
        float acc = b3s[m];
#pragma unroll
        for (int k = 0; k < 40; ++k) acc = fmaf(p[k], w3s[k * 50 + m], acc);
        float v = LEAKY(acc);
#pragma unroll
        for (int j = 0; j < 10; ++j) logits[j] = fmaf(v, wls[m * 10 + j], logits[j]);
    }
    float mx = logits[0];
#pragma unroll
    for (int j = 1; j < 10; ++j) mx = fmaxf(mx, logits[j]);
    float s = 0.0f;
#pragma unroll
    for (int j = 0; j < 10; ++j) s += __expf(logits[j] - mx);
    float lse = __logf(s) + mx;
    float* op = out + (size_t)n * 10;
#pragma unroll
    for (int j = 0; j < 10; ++j) op[j] = logits[j] - lse;
}

extern "C" void kernel_launch(void* const* d_in, const int* in_sizes, int n_in,
                              void* d_out, int out_size, void* d_ws, size_t ws_size,
                              hipStream_t stream) {
    const float* x  = (const float*)d_in[0];
    const unsigned* ei = (const unsigned*)d_in[1];
    const float* W1 = (const float*)d_in[2];
    const float* b1 = (const float*)d_in[3];
    const float* W2 = (const float*)d_in[4];
    const float* b2 = (const float*)d_in[5];
    const float* W3 = (const float*)d_in[6];
    const float* b3 = (const float*)d_in[7];
    const float* Wl = (const float*)d_in[8];
    const float* bl = (const float*)d_in[9];
    float* out = (float*)d_out;

    const int N = in_sizes[0] / 64;
    const int E = in_sizes[1] / 2;

    // counting-sort geometry
    int ch = 4096;
    int nblk = (E + ch - 1) / ch;
    if (nblk > 256) { ch = (E + 255) / 256; nblk = (E + ch - 1) / ch; }
    const int nbuk = (N + 255) >> 8;  // <= 512

    char* wp = (char*)d_ws;
    auto alloc = [&](size_t bytes) {
        char* p = wp;
        wp += (bytes + 255) & ~(size_t)255;
        return p;
    };
    int*   es      = (int*)alloc((size_t)E * 4);
    float* dinv    = (float*)alloc((size_t)N * 4);
    int*   row_ofs = (int*)alloc((size_t)(N + 1) * 4);
    int*   gcount  = (int*)alloc((size_t)nbuk * nblk * 4);
    int*   btot    = (int*)alloc((size_t)NBUK_MAX * 4);
    int*   bbase   = (int*)alloc((size_t)(NBUK_MAX + 1) * 4);
    char*  Pr      = (char*)alloc((size_t)N * 64 * 4);  // 25.6 MB region
    char*  Ar      = (char*)alloc((size_t)N * 80 * 4);  // 32 MB region

    // aliases (strictly sequential lifetimes):
    int*      s32    = (int*)Pr;                 // passes A-C
    int*      d32    = (int*)Pr + E;
    unsigned* es_tmp = (unsigned*)Ar;            // packed, passes C-D (E*4 B)
    size_t xb_off = (((size_t)E * 4) + 255) & ~(size_t)255;
    unsigned short* xb = (unsigned short*)(Ar + xb_off);  // bf16 x', dead after gather64
    unsigned short* Pg = (unsigned short*)Pr;    // gather64 out bf16 (12.8 MB); over s32/d32
    unsigned short* A  = (unsigned short*)Ar;    // gemm1 out bf16 (16 MB); over es_tmp+xb
    unsigned short* Pb = (unsigned short*)Pr;    // gemm2 out bf16 (8 MB); over Pg
    unsigned short* Ab = (unsigned short*)(Ar + (size_t)N * 80 * 4 - (size_t)N * 40 * 2);
    unsigned short* P3 = (unsigned short*)Pr;    // gather40-L3 out bf16 (8 MB); over Pb

    const int B = 256;

    // ---- CSR build: atomic-free counting sort (+fused x->bf16 cvt) ----
    bucket_count_kernel<<<nblk, B, 0, stream>>>(ei, s32, d32, gcount, E, nblk, nbuk, ch);
    bucket_total_kernel<<<nbuk, B, 0, stream>>>(gcount, btot, nblk);
    scan_btot_kernel<<<1, 512, 0, stream>>>(btot, bbase, row_ofs, nbuk, N, E);
    scan_gcount_kernel<<<nbuk, B, 0, stream>>>(gcount, bbase, nblk);
    bucket_scatter_kernel<<<nblk, B, 0, stream>>>(s32, d32, gcount, es_tmp, E, nblk, nbuk, ch);
    bucket_sortcvt_kernel<<<nbuk, B, 0, stream>>>(es_tmp, bbase, es, row_ofs, dinv,
                                                  x, (ushort4*)xb, N);

    const int gblocks = (N * 64 + B - 1) / B;  // one wave per node

    auto gb = [&](int M) {
        int MC = (M + 3) / 4;
        int BN = (256 / MC) * 4;
        return (N + BN - 1) / BN;
    };

    // L1: agg(xb) -> Pg bf16, then GEMM1 (+b1) -> A bf16
    gather64_bf16_kernel<<<gblocks, B, 0, stream>>>(xb, es, row_ofs, dinv, Pg, N);
    gemm_tiled_bf16<64, 80, false, true, false><<<gb(80), B, 0, stream>>>(Pg, W1, b1, nullptr, A, N);

    // L2: GEMM2: Pb = bf16((leaky(A)@W2)*dinv); gather(+b2) -> leaky*dinv -> Ab bf16
    gemm_tiled_bf16<80, 40, true, false, true><<<gb(40), B, 0, stream>>>(A, W2, nullptr, dinv, Pb, N);
    gather40_bf16_kernel<true, true><<<gblocks, B, 0, stream>>>(Pb, es, row_ofs, dinv, b2, Ab, N);

    // L3: agg(Ab) -> P3 bf16, then fused GEMM+head
    gather40_bf16_kernel<false, false><<<gblocks, B, 0, stream>>>(Ab, es, row_ofs, dinv, nullptr, P3, N);
    l3head_kernel<<<(N + B - 1) / B, B, 0, stream>>>(P3, W3, b3, Wl, bl, out, N);
}